// Round 8
// baseline (261.581 us; speedup 1.0000x reference)
//
#include <hip/hip_runtime.h>
#include <hip/hip_bf16.h>

typedef unsigned short u16;
typedef __attribute__((ext_vector_type(8))) short short8;
typedef __attribute__((ext_vector_type(4))) short short4_t;
typedef __attribute__((ext_vector_type(4))) float floatx4;

#define MFMA16(A, B, C) __builtin_amdgcn_mfma_f32_16x16x32_bf16((A), (B), (C), 0, 0, 0)

// ws layout (u16 element offsets)
#define OF_PART  64                        // 8x256 f32 partials for fused bp (4096 u16)
#define OF_FQKV  (OF_PART + 4096)          // fq,fk,fv f32 (3x256 -> 1536 u16)
#define OF_SORT  (OF_FQKV + 1536)          // 256 f32 sorted thresholds (512 u16)
#define OF_EVK   (OF_SORT + 512)           // 256 u16 sorted event k-indices
#define OF_CA    (OF_EVK + 256)            // 256 f32 event coefs for A tables (sg*w1)
#define OF_CB    (OF_CA + 512)             // 256 f32 event coefs for B tables (sg*b1)
#define OF_MA    (OF_CB + 512)             // 256 f32 base coefs A (act0 ? w1 : 0)
#define OF_MB    (OF_MA + 512)             // 256 f32 base coefs B (act0 ? b1 : 0)
#define OF_P2    (OF_MB + 512)             // scan partials f32 [6 tbl][8 chunk][2][256]
// QK interleaved table f32 [257][1024]: idx = r*1024 + (n>>3)*32 + t*8 + (n&7),
// t in {0:Aq,1:Bq,2:Ak,3:Bk}; then Av,Bv plain f32 [257][256] each.
#define OF_TAB   (OF_P2 + 49152)
#define NF_QK    263168                    // 257*1024 f32
#define NF_V     65792                     // 257*256 f32
#define OF_WP    (OF_TAB + 789504)         // Wp' bf16 frag-major (524288 u16)
#define OF_ORAW  (OF_WP + 524288)          // o_raw bf16 frag-major [256 kb8][25600 m][8]
#define OF_WQB   OF_ORAW                   // overlay: Wq'/Wk'/Wv' bf16 row-major (3x65536)
#define NPM8     204800                    // 25600 patches * 8

static __device__ __forceinline__ float bf2f(u16 u) {
  union { unsigned int i; float f; } z; z.i = ((unsigned int)u) << 16; return z.f;
}
static __device__ __forceinline__ u16 f2bf(float f) {
  union { float f; unsigned int i; } z; z.f = f;
  unsigned int x = z.i + 0x7fffu + ((z.i >> 16) & 1u);  // RNE
  return (u16)(x >> 16);
}
static __device__ __forceinline__ unsigned pkbf(float lo, float hi) {
  __hip_bfloat162 h = __float22bfloat162_rn(make_float2(lo, hi));  // v_cvt_pk_bf16_f32
  unsigned r; __builtin_memcpy(&r, &h, 4); return r;
}

// bf16 (0) vs f32 (1) input detection on first 256 u16 of spec; per-wave ballot.
static __device__ __forceinline__ int detect_flag(const u16* __restrict__ sp) {
  const int lane = threadIdx.x & 63;
  int bad = 0;
#pragma unroll
  for (int j = 0; j < 4; ++j) {
    u16 v = sp[lane * 4 + j];
    int e = (v >> 7) & 0xFF;
    bad += (e >= 137);
  }
  return (__popcll(__ballot(bad > 0)) >= 4) ? 1 : 0;
}

#define CV(src, idx) (flag ? f2bf(((const float*)(src))[idx]) : ((const u16*)(src))[idx])

// prep1: blocks 0..175: 11 fold GEMMs of 256x256x256 (16 sub-blocks of 64x64),
// B-tile staged through LDS (coalesced b128, pad 72 u16 / row):
//   g=0..2:  Wg' = W2 @ {Wq,Wk,Wv} -> bf16 row-major [k][n] at OF_WQB
//   g=3..10: Wp'_p = Wo @ Wp[p*256:...] -> bf16 frag-major at OF_WP
// blocks 176..186: fq/fk/fv (f32) + 8 f32 partials for fused bp.
// block  187: threshold sort + event/base coef tables (for the prefix scan).
__global__ void prep1_kernel(
    const void* spec, const void* W1, const void* b1, const void* W2,
    const void* Wq, const void* bq, const void* Wk, const void* bk, const void* Wv,
    const void* bv_, const void* Wo, const void* bo, const void* Wp, const void* b2,
    u16* __restrict__ ws) {
  const int flag = detect_flag((const u16*)spec);
  const int b = blockIdx.x, tid = threadIdx.x;
  __shared__ u16 Bs[32 * 72];
  if (b == 187) {
    // sort thresholds t_k = -b1_k/W1_k; emit event order + coefs.
    __shared__ float st[256];
    __shared__ int   sk[256];
    __shared__ float w1s[256], b1s[256];
    w1s[tid] = flag ? ((const float*)W1)[tid] : bf2f(((const u16*)W1)[tid]);
    b1s[tid] = flag ? ((const float*)b1)[tid] : bf2f(((const u16*)b1)[tid]);
    __syncthreads();
    {
      const float w = w1s[tid];
      st[tid] = (w != 0.f) ? (-b1s[tid] / w) : 1e30f;
      sk[tid] = tid;
    }
    for (int size = 2; size <= 256; size <<= 1) {
      for (int stride = size >> 1; stride > 0; stride >>= 1) {
        __syncthreads();
        const int ixj = tid ^ stride;
        if (ixj > tid) {
          const bool up = ((tid & size) == 0);
          float a = st[tid], bq2 = st[ixj];
          if (up ? (a > bq2) : (a < bq2)) {
            int ka = sk[tid];
            st[tid] = bq2; st[ixj] = a;
            sk[tid] = sk[ixj]; sk[ixj] = ka;
          }
        }
      }
    }
    __syncthreads();
    ((float*)(ws + OF_SORT))[tid] = st[tid];
    ws[OF_EVK + tid] = (u16)sk[tid];
    {
      const int ke = sk[tid];
      const float w = w1s[ke], bb = b1s[ke];
      const float sg = (w > 0.f) ? 1.f : ((w < 0.f) ? -1.f : 0.f);
      ((float*)(ws + OF_CA))[tid] = sg * w;
      ((float*)(ws + OF_CB))[tid] = sg * bb;
    }
    {
      const float wk = w1s[tid], bk2 = b1s[tid];
      const bool act0 = (wk < 0.f) || (wk == 0.f && bk2 > 0.f);
      ((float*)(ws + OF_MA))[tid] = act0 ? wk : 0.f;
      ((float*)(ws + OF_MB))[tid] = act0 ? bk2 : 0.f;
    }
    return;
  }
  if (b >= 176) {
    const int t = b - 176, n = tid;
    if (t < 3) {
      const void* SB = (t == 0) ? Wq : (t == 1) ? Wk : Wv;
      const void* bs = (t == 0) ? bq : (t == 1) ? bk : bv_;
      float acc;
      if (flag) {
        acc = ((const float*)bs)[n];
        const float* Bf = (const float*)SB; const float* b2f = (const float*)b2;
        for (int k = 0; k < 256; ++k) acc = fmaf(b2f[k], Bf[k * 256 + n], acc);
      } else {
        acc = bf2f(((const u16*)bs)[n]);
        const u16* Bh = (const u16*)SB; const u16* b2h = (const u16*)b2;
        for (int k = 0; k < 256; ++k) acc = fmaf(bf2f(b2h[k]), bf2f(Bh[k * 256 + n]), acc);
      }
      ((float*)(ws + OF_FQKV))[t * 256 + n] = acc;
    } else {
      const int p = t - 3;
      float acc = 0.f;
      if (flag) {
        const float* Wf = (const float*)Wp; const float* bf = (const float*)bo;
        for (int m = 0; m < 256; ++m) acc = fmaf(bf[m], Wf[(p * 256 + m) * 256 + n], acc);
      } else {
        const u16* Wh = (const u16*)Wp; const u16* bh = (const u16*)bo;
        for (int m = 0; m < 256; ++m)
          acc = fmaf(bf2f(bh[m]), bf2f(Wh[(p * 256 + m) * 256 + n]), acc);
      }
      ((float*)(ws + OF_PART))[p * 256 + n] = acc;
    }
    return;
  }
  // fold GEMMs
  const int g = b >> 4, sub = b & 15;
  const int r0 = (sub >> 2) * 64, c0 = (sub & 3) * 64;
  const void* SA = (g < 3) ? W2 : Wo;
  const void* SB = (g == 0) ? Wq : (g == 1) ? Wk : (g == 2) ? Wv : Wp;
  const int brow0 = (g < 3) ? 0 : (g - 3) * 256;
  const int w = tid >> 6, lane = tid & 63, l15 = lane & 15, quad = lane >> 4;
  const int arow = r0 + w * 16 + l15;
  const int srow = tid >> 3, sseg = tid & 7;   // staging: row 0..31, 8-col segment
  floatx4 acc[4];
#pragma unroll
  for (int ni = 0; ni < 4; ++ni) acc[ni] = (floatx4){0.f, 0.f, 0.f, 0.f};
  for (int kc = 0; kc < 8; ++kc) {
    __syncthreads();
    if (flag) {
      const float* Bf = (const float*)SB;
      const float* src = Bf + (brow0 + kc * 32 + srow) * 256 + c0 + sseg * 8;
      floatx4 f0 = *(const floatx4*)src, f1 = *(const floatx4*)(src + 4);
      union { short8 s8; unsigned u[4]; } t;
      t.u[0] = pkbf(f0[0], f0[1]); t.u[1] = pkbf(f0[2], f0[3]);
      t.u[2] = pkbf(f1[0], f1[1]); t.u[3] = pkbf(f1[2], f1[3]);
      *(short8*)(Bs + srow * 72 + sseg * 8) = t.s8;
    } else {
      const u16* Bh = (const u16*)SB;
      *(short8*)(Bs + srow * 72 + sseg * 8) =
          *(const short8*)(Bh + (brow0 + kc * 32 + srow) * 256 + c0 + sseg * 8);
    }
    __syncthreads();
    const int k0 = kc * 32 + quad * 8;
    union { short8 s8; u16 u[8]; } av;
    if (flag) {
      const float* A = (const float*)SA;
      floatx4 a0 = *(const floatx4*)(A + arow * 256 + k0);
      floatx4 a1 = *(const floatx4*)(A + arow * 256 + k0 + 4);
      av.u[0] = f2bf(a0[0]); av.u[1] = f2bf(a0[1]); av.u[2] = f2bf(a0[2]); av.u[3] = f2bf(a0[3]);
      av.u[4] = f2bf(a1[0]); av.u[5] = f2bf(a1[1]); av.u[6] = f2bf(a1[2]); av.u[7] = f2bf(a1[3]);
    } else {
      const u16* A = (const u16*)SA;
      av.s8 = *(const short8*)(A + arow * 256 + k0);
    }
#pragma unroll
    for (int ni = 0; ni < 4; ++ni) {
      union { short8 s8; u16 u[8]; } bu;
#pragma unroll
      for (int j = 0; j < 8; ++j) bu.u[j] = Bs[(quad * 8 + j) * 72 + ni * 16 + l15];
      acc[ni] = MFMA16(av.s8, bu.s8, acc[ni]);
    }
  }
  if (g < 3) {
    u16* dst = ws + OF_WQB + g * 65536;
#pragma unroll
    for (int ni = 0; ni < 4; ++ni) {
      const int n = c0 + ni * 16 + l15;
#pragma unroll
      for (int r = 0; r < 4; ++r) {
        const int k = r0 + w * 16 + quad * 4 + r;
        dst[k * 256 + n] = f2bf(acc[ni][r]);
      }
    }
  } else {
    u16* dst = ws + OF_WP;
#pragma unroll
    for (int ni = 0; ni < 4; ++ni) {
      const int n = c0 + ni * 16 + l15;
#pragma unroll
      for (int r = 0; r < 4; ++r) {
        const int k = brow0 + r0 + w * 16 + quad * 4 + r;
        dst[(k >> 3) * 2048 + n * 8 + (k & 7)] = f2bf(acc[ni][r]);
      }
    }
  }
}

// prep2a: scan partials. 48 blocks = 6 tables x 8 chunks; each block sums its
// 32 base terms and 32 event terms per column (independent coalesced loads).
__global__ void prep2a_kernel(u16* __restrict__ ws) {
  const int tbl = blockIdx.x >> 3, chunk = blockIdx.x & 7;
  const int n = threadIdx.x;
  const int m = tbl >> 1, isB = tbl & 1;
  const u16* S = ws + OF_WQB + m * 65536;
  const float* MC = (const float*)(ws + (isB ? OF_MB : OF_MA));
  const float* CC = (const float*)(ws + (isB ? OF_CB : OF_CA));
  const u16* EVK = ws + OF_EVK;
  float bacc = 0.f, eacc = 0.f;
#pragma unroll 8
  for (int j = 0; j < 32; ++j) {
    const int k = chunk * 32 + j;
    bacc = fmaf(MC[k], bf2f(S[k * 256 + n]), bacc);
    eacc = fmaf(CC[k], bf2f(S[EVK[k] * 256 + n]), eacc);
  }
  float* P = (float*)(ws + OF_P2);
  P[((tbl * 8 + chunk) * 2 + 0) * 256 + n] = bacc;
  P[((tbl * 8 + chunk) * 2 + 1) * 256 + n] = eacc;
}

// prep2b: 48 blocks = 6 tables x 8 segments. Seed cur from base partials +
// event-chunk prefix, then a 31/32-step local walk writing rows rlo..rlo+31
// (seg 7 also writes row 256). QK tables (tbl<4) stored interleaved:
// idx = r*1024 + (n>>3)*32 + tbl*8 + (n&7); V tables (4,5) plain [257][256].
__global__ void prep2b_kernel(u16* __restrict__ ws) {
  const int tbl = blockIdx.x >> 3, seg = blockIdx.x & 7;
  const int n = threadIdx.x;
  const int m = tbl >> 1, isB = tbl & 1;
  const u16* S = ws + OF_WQB + m * 65536;
  const float* CC = (const float*)(ws + (isB ? OF_CB : OF_CA));
  const u16* EVK = ws + OF_EVK;
  const float* P = (const float*)(ws + OF_P2);
  float cur = isB ? ((const float*)(ws + OF_FQKV))[m * 256 + n] : 0.f;
#pragma unroll
  for (int c = 0; c < 8; ++c) cur += P[((tbl * 8 + c) * 2 + 0) * 256 + n];
  for (int c = 0; c < seg; ++c) cur += P[((tbl * 8 + c) * 2 + 1) * 256 + n];
  float* TB = (float*)(ws + OF_TAB);
  const int rlo = seg * 32;
  const long roff = (tbl < 4) ? ((n >> 3) * 32 + tbl * 8 + (n & 7))
                              : (NF_QK + (tbl - 4) * NF_V + n);
  const int rstr = (tbl < 4) ? 1024 : 256;
  TB[(long)rlo * rstr + roff] = cur;
  const int nev = (seg == 7) ? 32 : 31;
  for (int i = 0; i < nev; ++i) {
    const int e = rlo + i;
    cur = fmaf(CC[e], bf2f(S[EVK[e] * 256 + n]), cur);
    TB[(long)(e + 1) * rstr + roff] = cur;
  }
}

// One block = 64 tokens = 8 windows. q/k/v from f32 threshold-rank tables
// (QK interleaved: 128 contiguous B per lane per head). Swapped QK^T; softmax
// lane-local; P redistributed to the PV A-fragment via 4 shfls (no LDS alias,
// heads pipeline freely). Raw o written frag-major to o_raw.
__global__ __launch_bounds__(256) void fused_lite_kernel(
    const void* __restrict__ spec, const float* __restrict__ tsort,
    const float* __restrict__ TQK, const float* __restrict__ tAv,
    const float* __restrict__ tBv,
    u16* __restrict__ oraw)
{
  __shared__ u16 vbT[16384];          // 64 tok x 256 dims transposed, swizzled (32 KB)
  __shared__ float sS[64];
  __shared__ int   sR[64];

  const int flag = detect_flag((const u16*)spec);
  const int tid = threadIdx.x;
  const int wave = tid >> 6, lane = tid & 63;
  const int l15 = lane & 15, quad = lane >> 4;
  const int tile0 = blockIdx.x * 64;
  const floatx4 zero4 = (floatx4){0.f, 0.f, 0.f, 0.f};

  // phase 0 (wave-local): token s and rank r = #{t < s}; 4 quads count 64 each,
  // combined with 2 shfl_xor. quad 0 publishes to sS/sR for the v-fill.
  const int tok = wave * 16 + l15;
  const float s_t = flag ? ((const float*)spec)[tile0 + tok]
                         : bf2f(((const u16*)spec)[tile0 + tok]);
  int r_t;
  {
    int cnt = 0;
#pragma unroll 8
    for (int j = 0; j < 64; ++j) cnt += (tsort[quad * 64 + j] < s_t) ? 1 : 0;
    cnt += __shfl_xor(cnt, 16);
    cnt += __shfl_xor(cnt, 32);
    r_t = cnt;
    if (quad == 0) { sS[tok] = s_t; sR[tok] = cnt; }
  }
  __syncthreads();

  // phase 1: v-fill, token-pairs. Thread (tp, db) handles tokens {2tp,2tp+1},
  // dims db*32..+32; packed b32 stores, conflict-free swizzle.
  {
    const int tp = tid & 31, db = tid >> 5;
    const int t0 = tp * 2, t1 = t0 + 1;
    const float s0 = sS[t0], s1 = sS[t1];
    const float* A0 = tAv + sR[t0] * 256;
    const float* B0 = tBv + sR[t0] * 256;
    const float* A1 = tAv + sR[t1] * 256;
    const float* B1 = tBv + sR[t1] * 256;
    unsigned* vbT32 = (unsigned*)vbT;
#pragma unroll
    for (int j = 0; j < 32; j += 4) {
      const int d = db * 32 + j;
      floatx4 a0 = *(const floatx4*)(A0 + d), b0 = *(const floatx4*)(B0 + d);
      floatx4 a1 = *(const floatx4*)(A1 + d), b1 = *(const floatx4*)(B1 + d);
#pragma unroll
      for (int e = 0; e < 4; ++e) {
        const int dd = d + e;
        vbT32[dd * 32 + ((((tp >> 2) ^ (dd & 7)) << 2) | (tp & 3))] =
            pkbf(fmaf(s0, a0[e], b0[e]), fmaf(s1, a1[e], b1[e]));
      }
    }
  }
  __syncthreads();

  // phase 2: attention. Wave w owns windows {2w, 2w+1}; heads independent.
  unsigned opk[32];
  {
    const int w2 = wave * 2;
    const int valid = ((l15 >> 3) == (quad >> 1));
    const float* tq = TQK + r_t * 1024 + quad * 32;   // + h*128: [Aq|Bq|Ak|Bk] x 8
    const int src0 = (quad & 1) * 32 + l15, src1 = src0 + 16;
#pragma unroll
    for (int h = 0; h < 8; ++h) {
      const float* bp8 = tq + h * 128;
      floatx4 qa0 = *(const floatx4*)(bp8),      qa1 = *(const floatx4*)(bp8 + 4);
      floatx4 qb0 = *(const floatx4*)(bp8 + 8),  qb1 = *(const floatx4*)(bp8 + 12);
      floatx4 ka0 = *(const floatx4*)(bp8 + 16), ka1 = *(const floatx4*)(bp8 + 20);
      floatx4 kb0 = *(const floatx4*)(bp8 + 24), kb1 = *(const floatx4*)(bp8 + 28);
      short8 qv, kv;
      {
        union { short8 s8; unsigned u[4]; } z;
        z.u[0] = pkbf(fmaf(s_t, qa0[0], qb0[0]), fmaf(s_t, qa0[1], qb0[1]));
        z.u[1] = pkbf(fmaf(s_t, qa0[2], qb0[2]), fmaf(s_t, qa0[3], qb0[3]));
        z.u[2] = pkbf(fmaf(s_t, qa1[0], qb1[0]), fmaf(s_t, qa1[1], qb1[1]));
        z.u[3] = pkbf(fmaf(s_t, qa1[2], qb1[2]), fmaf(s_t, qa1[3], qb1[3]));
        qv = z.s8;
      }
      {
        union { short8 s8; unsigned u[4]; } z;
        z.u[0] = pkbf(fmaf(s_t, ka0[0], kb0[0]), fmaf(s_t, ka0[1], kb0[1]));
        z.u[1] = pkbf(fmaf(s_t, ka0[2], kb0[2]), fmaf(s_t, ka0[3], kb0[3]));
        z.u[2] = pkbf(fmaf(s_t, ka1[0], kb1[0]), fmaf(s_t, ka1[1], kb1[1]));
        z.u[3] = pkbf(fmaf(s_t, ka1[2], kb1[2]), fmaf(s_t, ka1[3], kb1[3]));
        kv = z.s8;
      }
      // swapped: sc[r] = score[k = quad*4+r][q = l15]
      floatx4 sc = MFMA16(kv, qv, zero4);
      const float SC = 0.17677669529663687f;   // 1/sqrt(32)
      float s0 = sc[0] * SC, s1 = sc[1] * SC, s2 = sc[2] * SC, s3 = sc[3] * SC;
      float m4 = fmaxf(fmaxf(s0, s1), fmaxf(s2, s3));
      float mx = fmaxf(m4, __shfl_xor(m4, 16));
      float p0 = __expf(s0 - mx), p1 = __expf(s1 - mx);
      float p2 = __expf(s2 - mx), p3 = __expf(s3 - mx);
      float sm = (p0 + p1) + (p2 + p3);
      float su = sm + __shfl_xor(sm, 16);
      float inv = 1.f / su;
      unsigned pw0 = pkbf(valid ? p0 * inv : 0.f, valid ? p1 * inv : 0.f);
      unsigned pw1 = pkbf(valid ? p2 * inv : 0.f, valid ? p3 * inv : 0.f);
      // redistribute P[k][q] -> PV A-fragment (row=q=l15, k-dim=quad*8..+7)
      unsigned g0 = __shfl(pw0, src0), g1 = __shfl(pw1, src0);
      unsigned g2 = __shfl(pw0, src1), g3 = __shfl(pw1, src1);
      short8 pa = (short8){0, 0, 0, 0, 0, 0, 0, 0};
      if (quad < 2) {
        union { short8 s8; unsigned u[4]; } z;
        z.u[0] = g0; z.u[1] = g1; z.u[2] = g2; z.u[3] = g3;
        pa = z.s8;
      }
#pragma unroll
      for (int dh = 0; dh < 2; ++dh) {
        const int vcol = h * 32 + dh * 16 + l15;
        short8 vf = (short8){0, 0, 0, 0, 0, 0, 0, 0};
        if (quad < 2)
          vf = *(const short8*)(vbT + vcol * 64 + (((w2 + quad) ^ (vcol & 7)) << 3));
        floatx4 o = MFMA16(pa, vf, zero4);
        opk[(h * 2 + dh) * 2]     = pkbf(o[0], o[1]);
        opk[(h * 2 + dh) * 2 + 1] = pkbf(o[2], o[3]);
      }
    }
  }

  // phase 3: opk -> o_raw (global, fragment-major).
  // token row = quad*4+r -> win = 2*wave + (quad>>1), p = (quad&1)*4 + r;
  // D = h*32 + dh*16 + l15 -> e8 = h*4 + dh*2 + (l15>>3).
  {
    const int mbase = (blockIdx.x * 8 + wave * 2 + (quad >> 1)) * 8 + (l15 & 7);
    const int pb4 = (quad & 1) * 4;
#pragma unroll
    for (int h = 0; h < 8; ++h)
#pragma unroll
      for (int dh = 0; dh < 2; ++dh) {
        const int oi = (h * 2 + dh) * 2;
        const int e8 = h * 4 + dh * 2 + (l15 >> 3);
        const unsigned lo = opk[oi], hi = opk[oi + 1];
        oraw[((pb4 + 0) * 32 + e8) * NPM8 + mbase] = (u16)lo;
        oraw[((pb4 + 1) * 32 + e8) * NPM8 + mbase] = (u16)(lo >> 16);
        oraw[((pb4 + 2) * 32 + e8) * NPM8 + mbase] = (u16)hi;
        oraw[((pb4 + 3) * 32 + e8) * NPM8 + mbase] = (u16)(hi >> 16);
      }
  }
}

// Patch projection GEMM: [25600 x 2048] @ Wp' [2048 x 256] + fb.
// M-tile 64, N-tile 128, 4 waves each 64x32; A and B direct from global
// (both fragment-major, coalesced b128); no LDS.
__global__ __launch_bounds__(256) void patch_gemm_kernel(
    const u16* __restrict__ spec_raw,
    const u16* __restrict__ oraw, const u16* __restrict__ sWp,
    const void* __restrict__ bp, const float* __restrict__ part,
    void* __restrict__ out)
{
  const int flag = detect_flag(spec_raw);
  const int tid = threadIdx.x;
  const int wave = tid >> 6, lane = tid & 63;
  const int l15 = lane & 15, quad = lane >> 4;
  const int m0 = (blockIdx.x >> 1) * 64;
  const int n0 = (blockIdx.x & 1) * 128 + wave * 32;
  const floatx4 zero4 = (floatx4){0.f, 0.f, 0.f, 0.f};

  floatx4 acc[4][2];
#pragma unroll
  for (int mi = 0; mi < 4; ++mi)
#pragma unroll
    for (int ni = 0; ni < 2; ++ni) acc[mi][ni] = zero4;

  const u16* ap = oraw + quad * NPM8 + (m0 + l15) * 8;
  const u16* bpw = sWp + quad * 2048 + (n0 + l15) * 8;
#pragma unroll 4
  for (int kk = 0; kk < 64; ++kk) {
    short8 b0 = *(const short8*)(bpw);
    short8 b1 = *(const short8*)(bpw + 128);         // +16 cols
#pragma unroll
    for (int mi = 0; mi < 4; ++mi) {
      short8 a = *(const short8*)(ap + mi * 128);    // +16 rows per mi
      acc[mi][0] = MFMA16(a, b0, acc[mi][0]);
      acc[mi][1] = MFMA16(a, b1, acc[mi][1]);
    }
    ap += 4 * NPM8;
    bpw += 4 * 2048;
  }

  // epilogue: fb = bp + sum of the 8 bo@Wp_p partials (f32)
#pragma unroll
  for (int ni = 0; ni < 2; ++ni) {
    const int n = n0 + ni * 16 + l15;
    float bb = bf2f(CV(bp, n));
#pragma unroll
    for (int p = 0; p < 8; ++p) bb += part[p * 256 + n];
#pragma unroll
    for (int mi = 0; mi < 4; ++mi) {
      const int mr = m0 + mi * 16 + quad * 4;
      if (flag) {
        float* po = (float*)out;
#pragma unroll
        for (int r = 0; r < 4; ++r)
          po[(mr + r) * 256 + n] = acc[mi][ni][r] + bb;
      } else {
        u16* po = (u16*)out;
#pragma unroll
        for (int r = 0; r < 4; ++r)
          po[(mr + r) * 256 + n] = f2bf(acc[mi][ni][r] + bb);
      }
    }
  }
}

extern "C" void kernel_launch(void* const* d_in, const int* in_sizes, int n_in,
                              void* d_out, int out_size, void* d_ws, size_t ws_size,
                              hipStream_t stream) {
  (void)in_sizes; (void)n_in; (void)out_size; (void)ws_size;
  u16* ws = (u16*)d_ws;

  prep1_kernel<<<188, 256, 0, stream>>>(
      d_in[0], d_in[1], d_in[2], d_in[3],
      d_in[5], d_in[6], d_in[7], d_in[8], d_in[9], d_in[10],
      d_in[11], d_in[12], d_in[13], d_in[4], ws);
  prep2a_kernel<<<48, 256, 0, stream>>>(ws);
  prep2b_kernel<<<48, 256, 0, stream>>>(ws);
  const float* TB = (const float*)(ws + OF_TAB);
  fused_lite_kernel<<<3200, 256, 0, stream>>>(
      d_in[0], (const float*)(ws + OF_SORT),
      TB, TB + NF_QK, TB + NF_QK + NF_V,
      ws + OF_ORAW);
  patch_gemm_kernel<<<800, 256, 0, stream>>>(
      (const u16*)d_in[0],
      ws + OF_ORAW, ws + OF_WP,
      d_in[14], (const float*)(ws + OF_PART),
      d_out);
}

// Round 9
// 258.474 us; speedup vs baseline: 1.0120x; 1.0120x over previous
//
#include <hip/hip_runtime.h>
#include <hip/hip_bf16.h>

typedef unsigned short u16;
typedef __attribute__((ext_vector_type(8))) short short8;
typedef __attribute__((ext_vector_type(4))) short short4_t;
typedef __attribute__((ext_vector_type(4))) float floatx4;

#define MFMA16(A, B, C) __builtin_amdgcn_mfma_f32_16x16x32_bf16((A), (B), (C), 0, 0, 0)

// ws layout (u16 element offsets)
#define OF_PART  64                        // 8x256 f32 partials for fused bp (4096 u16)
#define OF_FQKV  (OF_PART + 4096)          // fq,fk,fv f32 (3x256 -> 1536 u16)
#define OF_SORT  (OF_FQKV + 1536)          // 256 f32 sorted thresholds (512 u16)
#define OF_EVK   (OF_SORT + 512)           // 256 u16 sorted event k-indices
#define OF_CA    (OF_EVK + 256)            // 256 f32 event coefs for A tables (sg*w1)
#define OF_CB    (OF_CA + 512)             // 256 f32 event coefs for B tables (sg*b1)
#define OF_MA    (OF_CB + 512)             // 256 f32 base coefs A (act0 ? w1 : 0)
#define OF_MB    (OF_MA + 512)             // 256 f32 base coefs B (act0 ? b1 : 0)
#define OF_P2    (OF_MB + 512)             // scan partials f32 [6 tbl][8 chunk][2][256]
// QK interleaved table f32 [257][1024]: idx = r*1024 + (n>>3)*32 + t*8 + (n&7),
// t in {0:Aq,1:Bq,2:Ak,3:Bk}; then Av,Bv plain f32 [257][256] each.
#define OF_TAB   (OF_P2 + 49152)
#define NF_QK    263168                    // 257*1024 f32
#define NF_V     65792                     // 257*256 f32
#define OF_WP    (OF_TAB + 789504)         // Wp' bf16 frag-major (524288 u16)
#define OF_ORAW  (OF_WP + 524288)          // o_raw bf16 frag-major [256 kb8][25600 m][8]
#define OF_WQB   OF_ORAW                   // overlay: Wq'/Wk'/Wv' bf16 row-major (3x65536)
#define NPM8     204800                    // 25600 patches * 8

static __device__ __forceinline__ float bf2f(u16 u) {
  union { unsigned int i; float f; } z; z.i = ((unsigned int)u) << 16; return z.f;
}
static __device__ __forceinline__ u16 f2bf(float f) {
  union { float f; unsigned int i; } z; z.f = f;
  unsigned int x = z.i + 0x7fffu + ((z.i >> 16) & 1u);  // RNE
  return (u16)(x >> 16);
}
static __device__ __forceinline__ unsigned pkbf(float lo, float hi) {
  __hip_bfloat162 h = __float22bfloat162_rn(make_float2(lo, hi));  // v_cvt_pk_bf16_f32
  unsigned r; __builtin_memcpy(&r, &h, 4); return r;
}

// bf16 (0) vs f32 (1) input detection on first 256 u16 of spec; per-wave ballot.
static __device__ __forceinline__ int detect_flag(const u16* __restrict__ sp) {
  const int lane = threadIdx.x & 63;
  int bad = 0;
#pragma unroll
  for (int j = 0; j < 4; ++j) {
    u16 v = sp[lane * 4 + j];
    int e = (v >> 7) & 0xFF;
    bad += (e >= 137);
  }
  return (__popcll(__ballot(bad > 0)) >= 4) ? 1 : 0;
}

#define CV(src, idx) (flag ? f2bf(((const float*)(src))[idx]) : ((const u16*)(src))[idx])

// prep1: blocks 0..175: 11 fold GEMMs of 256x256x256 (16 sub-blocks of 64x64),
// B-tile staged through LDS (coalesced b128, pad 72 u16 / row):
//   g=0..2:  Wg' = W2 @ {Wq,Wk,Wv} -> bf16 row-major [k][n] at OF_WQB
//   g=3..10: Wp'_p = Wo @ Wp[p*256:...] -> bf16 frag-major at OF_WP
// blocks 176..186: fq/fk/fv (f32) + 8 f32 partials for fused bp.
// block  187: threshold sort + event/base coef tables (for the prefix scan).
__global__ void prep1_kernel(
    const void* spec, const void* W1, const void* b1, const void* W2,
    const void* Wq, const void* bq, const void* Wk, const void* bk, const void* Wv,
    const void* bv_, const void* Wo, const void* bo, const void* Wp, const void* b2,
    u16* __restrict__ ws) {
  const int flag = detect_flag((const u16*)spec);
  const int b = blockIdx.x, tid = threadIdx.x;
  __shared__ u16 Bs[32 * 72];
  if (b == 187) {
    // sort thresholds t_k = -b1_k/W1_k; emit event order + coefs.
    __shared__ float st[256];
    __shared__ int   sk[256];
    __shared__ float w1s[256], b1s[256];
    w1s[tid] = flag ? ((const float*)W1)[tid] : bf2f(((const u16*)W1)[tid]);
    b1s[tid] = flag ? ((const float*)b1)[tid] : bf2f(((const u16*)b1)[tid]);
    __syncthreads();
    {
      const float w = w1s[tid];
      st[tid] = (w != 0.f) ? (-b1s[tid] / w) : 1e30f;
      sk[tid] = tid;
    }
    for (int size = 2; size <= 256; size <<= 1) {
      for (int stride = size >> 1; stride > 0; stride >>= 1) {
        __syncthreads();
        const int ixj = tid ^ stride;
        if (ixj > tid) {
          const bool up = ((tid & size) == 0);
          float a = st[tid], bq2 = st[ixj];
          if (up ? (a > bq2) : (a < bq2)) {
            int ka = sk[tid];
            st[tid] = bq2; st[ixj] = a;
            sk[tid] = sk[ixj]; sk[ixj] = ka;
          }
        }
      }
    }
    __syncthreads();
    ((float*)(ws + OF_SORT))[tid] = st[tid];
    ws[OF_EVK + tid] = (u16)sk[tid];
    {
      const int ke = sk[tid];
      const float w = w1s[ke], bb = b1s[ke];
      const float sg = (w > 0.f) ? 1.f : ((w < 0.f) ? -1.f : 0.f);
      ((float*)(ws + OF_CA))[tid] = sg * w;
      ((float*)(ws + OF_CB))[tid] = sg * bb;
    }
    {
      const float wk = w1s[tid], bk2 = b1s[tid];
      const bool act0 = (wk < 0.f) || (wk == 0.f && bk2 > 0.f);
      ((float*)(ws + OF_MA))[tid] = act0 ? wk : 0.f;
      ((float*)(ws + OF_MB))[tid] = act0 ? bk2 : 0.f;
    }
    return;
  }
  if (b >= 176) {
    const int t = b - 176, n = tid;
    if (t < 3) {
      const void* SB = (t == 0) ? Wq : (t == 1) ? Wk : Wv;
      const void* bs = (t == 0) ? bq : (t == 1) ? bk : bv_;
      float acc;
      if (flag) {
        acc = ((const float*)bs)[n];
        const float* Bf = (const float*)SB; const float* b2f = (const float*)b2;
        for (int k = 0; k < 256; ++k) acc = fmaf(b2f[k], Bf[k * 256 + n], acc);
      } else {
        acc = bf2f(((const u16*)bs)[n]);
        const u16* Bh = (const u16*)SB; const u16* b2h = (const u16*)b2;
        for (int k = 0; k < 256; ++k) acc = fmaf(bf2f(b2h[k]), bf2f(Bh[k * 256 + n]), acc);
      }
      ((float*)(ws + OF_FQKV))[t * 256 + n] = acc;
    } else {
      const int p = t - 3;
      float acc = 0.f;
      if (flag) {
        const float* Wf = (const float*)Wp; const float* bf = (const float*)bo;
        for (int m = 0; m < 256; ++m) acc = fmaf(bf[m], Wf[(p * 256 + m) * 256 + n], acc);
      } else {
        const u16* Wh = (const u16*)Wp; const u16* bh = (const u16*)bo;
        for (int m = 0; m < 256; ++m)
          acc = fmaf(bf2f(bh[m]), bf2f(Wh[(p * 256 + m) * 256 + n]), acc);
      }
      ((float*)(ws + OF_PART))[p * 256 + n] = acc;
    }
    return;
  }
  // fold GEMMs
  const int g = b >> 4, sub = b & 15;
  const int r0 = (sub >> 2) * 64, c0 = (sub & 3) * 64;
  const void* SA = (g < 3) ? W2 : Wo;
  const void* SB = (g == 0) ? Wq : (g == 1) ? Wk : (g == 2) ? Wv : Wp;
  const int brow0 = (g < 3) ? 0 : (g - 3) * 256;
  const int w = tid >> 6, lane = tid & 63, l15 = lane & 15, quad = lane >> 4;
  const int arow = r0 + w * 16 + l15;
  const int srow = tid >> 3, sseg = tid & 7;   // staging: row 0..31, 8-col segment
  floatx4 acc[4];
#pragma unroll
  for (int ni = 0; ni < 4; ++ni) acc[ni] = (floatx4){0.f, 0.f, 0.f, 0.f};
  for (int kc = 0; kc < 8; ++kc) {
    __syncthreads();
    if (flag) {
      const float* Bf = (const float*)SB;
      const float* src = Bf + (brow0 + kc * 32 + srow) * 256 + c0 + sseg * 8;
      floatx4 f0 = *(const floatx4*)src, f1 = *(const floatx4*)(src + 4);
      union { short8 s8; unsigned u[4]; } t;
      t.u[0] = pkbf(f0[0], f0[1]); t.u[1] = pkbf(f0[2], f0[3]);
      t.u[2] = pkbf(f1[0], f1[1]); t.u[3] = pkbf(f1[2], f1[3]);
      *(short8*)(Bs + srow * 72 + sseg * 8) = t.s8;
    } else {
      const u16* Bh = (const u16*)SB;
      *(short8*)(Bs + srow * 72 + sseg * 8) =
          *(const short8*)(Bh + (brow0 + kc * 32 + srow) * 256 + c0 + sseg * 8);
    }
    __syncthreads();
    const int k0 = kc * 32 + quad * 8;
    union { short8 s8; u16 u[8]; } av;
    if (flag) {
      const float* A = (const float*)SA;
      floatx4 a0 = *(const floatx4*)(A + arow * 256 + k0);
      floatx4 a1 = *(const floatx4*)(A + arow * 256 + k0 + 4);
      av.u[0] = f2bf(a0[0]); av.u[1] = f2bf(a0[1]); av.u[2] = f2bf(a0[2]); av.u[3] = f2bf(a0[3]);
      av.u[4] = f2bf(a1[0]); av.u[5] = f2bf(a1[1]); av.u[6] = f2bf(a1[2]); av.u[7] = f2bf(a1[3]);
    } else {
      const u16* A = (const u16*)SA;
      av.s8 = *(const short8*)(A + arow * 256 + k0);
    }
#pragma unroll
    for (int ni = 0; ni < 4; ++ni) {
      union { short8 s8; u16 u[8]; } bu;
#pragma unroll
      for (int j = 0; j < 8; ++j) bu.u[j] = Bs[(quad * 8 + j) * 72 + ni * 16 + l15];
      acc[ni] = MFMA16(av.s8, bu.s8, acc[ni]);
    }
  }
  if (g < 3) {
    u16* dst = ws + OF_WQB + g * 65536;
#pragma unroll
    for (int ni = 0; ni < 4; ++ni) {
      const int n = c0 + ni * 16 + l15;
#pragma unroll
      for (int r = 0; r < 4; ++r) {
        const int k = r0 + w * 16 + quad * 4 + r;
        dst[k * 256 + n] = f2bf(acc[ni][r]);
      }
    }
  } else {
    u16* dst = ws + OF_WP;
#pragma unroll
    for (int ni = 0; ni < 4; ++ni) {
      const int n = c0 + ni * 16 + l15;
#pragma unroll
      for (int r = 0; r < 4; ++r) {
        const int k = brow0 + r0 + w * 16 + quad * 4 + r;
        dst[(k >> 3) * 2048 + n * 8 + (k & 7)] = f2bf(acc[ni][r]);
      }
    }
  }
}

// prep2a: scan partials. 48 blocks = 6 tables x 8 chunks; each block sums its
// 32 base terms and 32 event terms per column (independent coalesced loads).
__global__ void prep2a_kernel(u16* __restrict__ ws) {
  const int tbl = blockIdx.x >> 3, chunk = blockIdx.x & 7;
  const int n = threadIdx.x;
  const int m = tbl >> 1, isB = tbl & 1;
  const u16* S = ws + OF_WQB + m * 65536;
  const float* MC = (const float*)(ws + (isB ? OF_MB : OF_MA));
  const float* CC = (const float*)(ws + (isB ? OF_CB : OF_CA));
  const u16* EVK = ws + OF_EVK;
  float bacc = 0.f, eacc = 0.f;
#pragma unroll 8
  for (int j = 0; j < 32; ++j) {
    const int k = chunk * 32 + j;
    bacc = fmaf(MC[k], bf2f(S[k * 256 + n]), bacc);
    eacc = fmaf(CC[k], bf2f(S[EVK[k] * 256 + n]), eacc);
  }
  float* P = (float*)(ws + OF_P2);
  P[((tbl * 8 + chunk) * 2 + 0) * 256 + n] = bacc;
  P[((tbl * 8 + chunk) * 2 + 1) * 256 + n] = eacc;
}

// prep2b: 48 blocks = 6 tables x 8 segments. Seed cur from base partials +
// event-chunk prefix, then a 31/32-step local walk writing rows rlo..rlo+31
// (seg 7 also writes row 256). QK tables (tbl<4) stored interleaved:
// idx = r*1024 + (n>>3)*32 + tbl*8 + (n&7); V tables (4,5) plain [257][256].
__global__ void prep2b_kernel(u16* __restrict__ ws) {
  const int tbl = blockIdx.x >> 3, seg = blockIdx.x & 7;
  const int n = threadIdx.x;
  const int m = tbl >> 1, isB = tbl & 1;
  const u16* S = ws + OF_WQB + m * 65536;
  const float* CC = (const float*)(ws + (isB ? OF_CB : OF_CA));
  const u16* EVK = ws + OF_EVK;
  const float* P = (const float*)(ws + OF_P2);
  float cur = isB ? ((const float*)(ws + OF_FQKV))[m * 256 + n] : 0.f;
#pragma unroll
  for (int c = 0; c < 8; ++c) cur += P[((tbl * 8 + c) * 2 + 0) * 256 + n];
  for (int c = 0; c < seg; ++c) cur += P[((tbl * 8 + c) * 2 + 1) * 256 + n];
  float* TB = (float*)(ws + OF_TAB);
  const int rlo = seg * 32;
  const long roff = (tbl < 4) ? ((n >> 3) * 32 + tbl * 8 + (n & 7))
                              : (NF_QK + (tbl - 4) * NF_V + n);
  const int rstr = (tbl < 4) ? 1024 : 256;
  TB[(long)rlo * rstr + roff] = cur;
  const int nev = (seg == 7) ? 32 : 31;
  for (int i = 0; i < nev; ++i) {
    const int e = rlo + i;
    cur = fmaf(CC[e], bf2f(S[EVK[e] * 256 + n]), cur);
    TB[(long)(e + 1) * rstr + roff] = cur;
  }
}

// One block = 128 threads = 2 waves = 32 tokens = 4 windows (16.6 KB LDS ->
// ~9 blocks/CU). Per-wave code identical to round 8; only the V buffer is
// 32-token sized with addr(d,tp) = (d>>1)*32 + (d&1)*16 + (tp ^ ((d&3)<<2)).
__global__ __launch_bounds__(128) void fused_lite_kernel(
    const void* __restrict__ spec, const float* __restrict__ tsort,
    const float* __restrict__ TQK, const float* __restrict__ tAv,
    const float* __restrict__ tBv,
    u16* __restrict__ oraw)
{
  __shared__ unsigned vbT32[4096];    // 16 KB: V bf16-pairs [256 dims][16 tok-pairs]
  __shared__ float sS[32];
  __shared__ int   sR[32];

  const int flag = detect_flag((const u16*)spec);
  const int tid = threadIdx.x;
  const int wave = tid >> 6, lane = tid & 63;
  const int l15 = lane & 15, quad = lane >> 4;
  const int tile0 = blockIdx.x * 32;
  const floatx4 zero4 = (floatx4){0.f, 0.f, 0.f, 0.f};

  // phase 0 (wave-local): token s and rank r = #{t < s}; 4 quads count 64 each,
  // combined with 2 shfl_xor. quad 0 publishes to sS/sR for the v-fill.
  const int tok = wave * 16 + l15;
  const float s_t = flag ? ((const float*)spec)[tile0 + tok]
                         : bf2f(((const u16*)spec)[tile0 + tok]);
  int r_t;
  {
    int cnt = 0;
#pragma unroll 8
    for (int j = 0; j < 64; ++j) cnt += (tsort[quad * 64 + j] < s_t) ? 1 : 0;
    cnt += __shfl_xor(cnt, 16);
    cnt += __shfl_xor(cnt, 32);
    r_t = cnt;
    if (quad == 0) { sS[tok] = s_t; sR[tok] = cnt; }
  }
  __syncthreads();

  // phase 1: v-fill. Thread (tp = tid&15, db = tid>>4) handles tokens
  // {2tp, 2tp+1}, dims db*32..+32; packed b32 stores.
  {
    const int tp = tid & 15, db = tid >> 4;
    const int t0 = tp * 2, t1 = t0 + 1;
    const float s0 = sS[t0], s1 = sS[t1];
    const float* A0 = tAv + sR[t0] * 256;
    const float* B0 = tBv + sR[t0] * 256;
    const float* A1 = tAv + sR[t1] * 256;
    const float* B1 = tBv + sR[t1] * 256;
#pragma unroll
    for (int jj = 0; jj < 32; jj += 4) {
      const int d = db * 32 + jj;
      floatx4 a0 = *(const floatx4*)(A0 + d), b0 = *(const floatx4*)(B0 + d);
      floatx4 a1 = *(const floatx4*)(A1 + d), b1 = *(const floatx4*)(B1 + d);
#pragma unroll
      for (int e = 0; e < 4; ++e) {
        const int dd = d + e;
        vbT32[(dd >> 1) * 32 + (dd & 1) * 16 + (tp ^ ((dd & 3) << 2))] =
            pkbf(fmaf(s0, a0[e], b0[e]), fmaf(s1, a1[e], b1[e]));
      }
    }
  }
  __syncthreads();

  // phase 2: attention. Wave w owns windows {2w, 2w+1}; heads independent.
  unsigned opk[32];
  {
    const int valid = ((l15 >> 3) == (quad >> 1));
    const float* tq = TQK + r_t * 1024 + quad * 32;   // + h*128: [Aq|Bq|Ak|Bk] x 8
    const int src0 = (quad & 1) * 32 + l15, src1 = src0 + 16;
#pragma unroll
    for (int h = 0; h < 8; ++h) {
      const float* bp8 = tq + h * 128;
      floatx4 qa0 = *(const floatx4*)(bp8),      qa1 = *(const floatx4*)(bp8 + 4);
      floatx4 qb0 = *(const floatx4*)(bp8 + 8),  qb1 = *(const floatx4*)(bp8 + 12);
      floatx4 ka0 = *(const floatx4*)(bp8 + 16), ka1 = *(const floatx4*)(bp8 + 20);
      floatx4 kb0 = *(const floatx4*)(bp8 + 24), kb1 = *(const floatx4*)(bp8 + 28);
      short8 qv, kv;
      {
        union { short8 s8; unsigned u[4]; } z;
        z.u[0] = pkbf(fmaf(s_t, qa0[0], qb0[0]), fmaf(s_t, qa0[1], qb0[1]));
        z.u[1] = pkbf(fmaf(s_t, qa0[2], qb0[2]), fmaf(s_t, qa0[3], qb0[3]));
        z.u[2] = pkbf(fmaf(s_t, qa1[0], qb1[0]), fmaf(s_t, qa1[1], qb1[1]));
        z.u[3] = pkbf(fmaf(s_t, qa1[2], qb1[2]), fmaf(s_t, qa1[3], qb1[3]));
        qv = z.s8;
      }
      {
        union { short8 s8; unsigned u[4]; } z;
        z.u[0] = pkbf(fmaf(s_t, ka0[0], kb0[0]), fmaf(s_t, ka0[1], kb0[1]));
        z.u[1] = pkbf(fmaf(s_t, ka0[2], kb0[2]), fmaf(s_t, ka0[3], kb0[3]));
        z.u[2] = pkbf(fmaf(s_t, ka1[0], kb1[0]), fmaf(s_t, ka1[1], kb1[1]));
        z.u[3] = pkbf(fmaf(s_t, ka1[2], kb1[2]), fmaf(s_t, ka1[3], kb1[3]));
        kv = z.s8;
      }
      // swapped: sc[r] = score[k = quad*4+r][q = l15]
      floatx4 sc = MFMA16(kv, qv, zero4);
      const float SC = 0.17677669529663687f;   // 1/sqrt(32)
      float s0 = sc[0] * SC, s1 = sc[1] * SC, s2 = sc[2] * SC, s3 = sc[3] * SC;
      float m4 = fmaxf(fmaxf(s0, s1), fmaxf(s2, s3));
      float mx = fmaxf(m4, __shfl_xor(m4, 16));
      float p0 = __expf(s0 - mx), p1 = __expf(s1 - mx);
      float p2 = __expf(s2 - mx), p3 = __expf(s3 - mx);
      float sm = (p0 + p1) + (p2 + p3);
      float su = sm + __shfl_xor(sm, 16);
      float inv = 1.f / su;
      unsigned pw0 = pkbf(valid ? p0 * inv : 0.f, valid ? p1 * inv : 0.f);
      unsigned pw1 = pkbf(valid ? p2 * inv : 0.f, valid ? p3 * inv : 0.f);
      // redistribute P[k][q] -> PV A-fragment (row=q=l15, k-dim=quad*8..+7)
      unsigned g0 = __shfl(pw0, src0), g1 = __shfl(pw1, src0);
      unsigned g2 = __shfl(pw0, src1), g3 = __shfl(pw1, src1);
      short8 pa = (short8){0, 0, 0, 0, 0, 0, 0, 0};
      if (quad < 2) {
        union { short8 s8; unsigned u[4]; } z;
        z.u[0] = g0; z.u[1] = g1; z.u[2] = g2; z.u[3] = g3;
        pa = z.s8;
      }
#pragma unroll
      for (int dh = 0; dh < 2; ++dh) {
        const int vcol = h * 32 + dh * 16 + l15;
        short8 vf = (short8){0, 0, 0, 0, 0, 0, 0, 0};
        if (quad < 2)
          vf = *(const short8*)((const u16*)(vbT32 + (vcol >> 1) * 32 +
                (vcol & 1) * 16 + ((wave * 8 + quad * 4) ^ ((vcol & 3) << 2))));
        floatx4 o = MFMA16(pa, vf, zero4);
        opk[(h * 2 + dh) * 2]     = pkbf(o[0], o[1]);
        opk[(h * 2 + dh) * 2 + 1] = pkbf(o[2], o[3]);
      }
    }
  }

  // phase 3: opk -> o_raw (global, fragment-major).
  // token row = quad*4+r -> win = 2*wave + (quad>>1), p = (quad&1)*4 + r;
  // D = h*32 + dh*16 + l15 -> e8 = h*4 + dh*2 + (l15>>3).
  {
    const int mbase = (blockIdx.x * 4 + wave * 2 + (quad >> 1)) * 8 + (l15 & 7);
    const int pb4 = (quad & 1) * 4;
#pragma unroll
    for (int h = 0; h < 8; ++h)
#pragma unroll
      for (int dh = 0; dh < 2; ++dh) {
        const int oi = (h * 2 + dh) * 2;
        const int e8 = h * 4 + dh * 2 + (l15 >> 3);
        const unsigned lo = opk[oi], hi = opk[oi + 1];
        oraw[((pb4 + 0) * 32 + e8) * NPM8 + mbase] = (u16)lo;
        oraw[((pb4 + 1) * 32 + e8) * NPM8 + mbase] = (u16)(lo >> 16);
        oraw[((pb4 + 2) * 32 + e8) * NPM8 + mbase] = (u16)hi;
        oraw[((pb4 + 3) * 32 + e8) * NPM8 + mbase] = (u16)(hi >> 16);
      }
  }
}

// Patch projection GEMM: [25600 x 2048] @ Wp' [2048 x 256] + fb.
// M-tile 64, N-tile 128, 4 waves each 64x32; A and B direct from global
// (both fragment-major, coalesced b128); no LDS.
__global__ __launch_bounds__(256) void patch_gemm_kernel(
    const u16* __restrict__ spec_raw,
    const u16* __restrict__ oraw, const u16* __restrict__ sWp,
    const void* __restrict__ bp, const float* __restrict__ part,
    void* __restrict__ out)
{
  const int flag = detect_flag(spec_raw);
  const int tid = threadIdx.x;
  const int wave = tid >> 6, lane = tid & 63;
  const int l15 = lane & 15, quad = lane >> 4;
  const int m0 = (blockIdx.x >> 1) * 64;
  const int n0 = (blockIdx.x & 1) * 128 + wave * 32;
  const floatx4 zero4 = (floatx4){0.f, 0.f, 0.f, 0.f};

  floatx4 acc[4][2];
#pragma unroll
  for (int mi = 0; mi < 4; ++mi)
#pragma unroll
    for (int ni = 0; ni < 2; ++ni) acc[mi][ni] = zero4;

  const u16* ap = oraw + quad * NPM8 + (m0 + l15) * 8;
  const u16* bpw = sWp + quad * 2048 + (n0 + l15) * 8;
#pragma unroll 4
  for (int kk = 0; kk < 64; ++kk) {
    short8 b0 = *(const short8*)(bpw);
    short8 b1 = *(const short8*)(bpw + 128);         // +16 cols
#pragma unroll
    for (int mi = 0; mi < 4; ++mi) {
      short8 a = *(const short8*)(ap + mi * 128);    // +16 rows per mi
      acc[mi][0] = MFMA16(a, b0, acc[mi][0]);
      acc[mi][1] = MFMA16(a, b1, acc[mi][1]);
    }
    ap += 4 * NPM8;
    bpw += 4 * 2048;
  }

  // epilogue: fb = bp + sum of the 8 bo@Wp_p partials (f32)
#pragma unroll
  for (int ni = 0; ni < 2; ++ni) {
    const int n = n0 + ni * 16 + l15;
    float bb = bf2f(CV(bp, n));
#pragma unroll
    for (int p = 0; p < 8; ++p) bb += part[p * 256 + n];
#pragma unroll
    for (int mi = 0; mi < 4; ++mi) {
      const int mr = m0 + mi * 16 + quad * 4;
      if (flag) {
        float* po = (float*)out;
#pragma unroll
        for (int r = 0; r < 4; ++r)
          po[(mr + r) * 256 + n] = acc[mi][ni][r] + bb;
      } else {
        u16* po = (u16*)out;
#pragma unroll
        for (int r = 0; r < 4; ++r)
          po[(mr + r) * 256 + n] = f2bf(acc[mi][ni][r] + bb);
      }
    }
  }
}

extern "C" void kernel_launch(void* const* d_in, const int* in_sizes, int n_in,
                              void* d_out, int out_size, void* d_ws, size_t ws_size,
                              hipStream_t stream) {
  (void)in_sizes; (void)n_in; (void)out_size; (void)ws_size;
  u16* ws = (u16*)d_ws;

  prep1_kernel<<<188, 256, 0, stream>>>(
      d_in[0], d_in[1], d_in[2], d_in[3],
      d_in[5], d_in[6], d_in[7], d_in[8], d_in[9], d_in[10],
      d_in[11], d_in[12], d_in[13], d_in[4], ws);
  prep2a_kernel<<<48, 256, 0, stream>>>(ws);
  prep2b_kernel<<<48, 256, 0, stream>>>(ws);
  const float* TB = (const float*)(ws + OF_TAB);
  fused_lite_kernel<<<6400, 128, 0, stream>>>(
      d_in[0], (const float*)(ws + OF_SORT),
      TB, TB + NF_QK, TB + NF_QK + NF_V,
      ws + OF_ORAW);
  patch_gemm_kernel<<<800, 256, 0, stream>>>(
      (const u16*)d_in[0],
      ws + OF_ORAW, ws + OF_WP,
      d_in[14], (const float*)(ws + OF_PART),
      d_out);
}